// Round 1
// baseline (1277.858 us; speedup 1.0000x reference)
//
#include <hip/hip_runtime.h>

typedef unsigned short ushort_t;
typedef unsigned int uint_t;

using f32x4  = __attribute__((ext_vector_type(4))) float;
using bf16x8 = __attribute__((ext_vector_type(8))) short;

#define GLOAD_LDS16(gsrc, ldst) \
  __builtin_amdgcn_global_load_lds((const __attribute__((address_space(1))) void*)(gsrc), \
                                   (__attribute__((address_space(3))) void*)(ldst), 16, 0, 0)

__device__ __forceinline__ ushort_t f2bf(float f) {
  union { float f; uint_t u; } v; v.f = f;
  uint_t r = (v.u + 0x7FFFu + ((v.u >> 16) & 1u)) >> 16;
  return (ushort_t)r;
}

static constexpr int NROWS = 65536;
static constexpr int DIM   = 1024;
static constexpr int HID   = 2048;
static constexpr int NB    = 8;
static constexpr int RLORA = 16;
static constexpr int KE1   = DIM + NB * RLORA;   // 1152
static constexpr int KE2   = HID + NB * RLORA;   // 2176

// ---------------- prep kernels ----------------

// x_with_band (NROWS x 1025 f32) -> x_ext bf16 (cols 0..1023, stride KE1) + band[]
__global__ void repack_kernel(const float* __restrict__ xb,
                              ushort_t* __restrict__ xext,
                              int* __restrict__ band) {
  const int NPAIR = NROWS * (DIM / 2);
  for (int p = blockIdx.x * blockDim.x + threadIdx.x; p < NPAIR;
       p += gridDim.x * blockDim.x) {
    int row = p >> 9;           // DIM/2 = 512 pairs per row
    int cp  = p & 511;
    const float* src = xb + (size_t)row * (DIM + 1) + cp * 2;
    uint_t lo = f2bf(src[0]);
    uint_t hi = f2bf(src[1]);
    *(uint_t*)(xext + (size_t)row * KE1 + cp * 2) = lo | (hi << 16);
    if (cp == 0) band[row] = (int)src[DIM];   // src == row start here
  }
}

// W (K x Nn f32, row-major) -> Wt (Nn x Kext bf16): Wt[n][k] = W[k][n]
__global__ void transpose_f2bf(const float* __restrict__ W,
                               ushort_t* __restrict__ Wt,
                               int K, int Nn, int Kext) {
  __shared__ float t[32][33];
  const int tx = threadIdx.x, ty = threadIdx.y;      // 32 x 8
  const int k0 = blockIdx.x * 32, n0 = blockIdx.y * 32;
#pragma unroll
  for (int i = 0; i < 4; ++i)
    t[ty + i * 8][tx] = W[(size_t)(k0 + ty + i * 8) * Nn + n0 + tx];
  __syncthreads();
#pragma unroll
  for (int i = 0; i < 4; ++i)
    Wt[(size_t)(n0 + ty + i * 8) * Kext + k0 + tx] = f2bf(t[tx][ty + i * 8]);
}

// Append Bm (NB x 16 x Nn f32) into K-tail of Wt: Wt[n][K + b*16 + r] = Bm[b][r][n]
__global__ void wt_tail(const float* __restrict__ Bm,
                        ushort_t* __restrict__ Wt,
                        int Nn, int Kext, int K) {
  const int n = blockIdx.x;
  const int c = threadIdx.x;   // 0..127
  Wt[(size_t)n * Kext + K + c] =
      f2bf(Bm[(size_t)(c >> 4) * 16 * Nn + (size_t)(c & 15) * Nn + n]);
}

// A (NB x Dd x 16 f32) -> At (128 x Dd bf16): At[b*16+r][d] = A[b][d][r]
__global__ void at_build(const float* __restrict__ Asrc,
                         ushort_t* __restrict__ At, int Dd) {
  const int c = blockIdx.y;                       // 0..127
  const int d = blockIdx.x * 256 + threadIdx.x;   // 0..Dd-1
  At[(size_t)c * Dd + d] =
      f2bf(Asrc[(size_t)(c >> 4) * Dd * 16 + (size_t)d * 16 + (c & 15)]);
}

// ---------------- main GEMM ----------------
// C[M x Ncols] = A[M x K] @ Bt[Ncols x K]^T  (both bf16, row-major, strides lda/ldb)
// 128x128 tile, BK=64, 4 waves (2x2), 16x16x32 bf16 MFMA, m97 structure with
// global_load_lds(16B) + XOR chunk-swizzle (applied on global SOURCE, read-side XOR).
// EPI 0: lora-mask write  -> bf16 dst[row*ldc + ocol0 + col], masked by band, x2.0
// EPI 1: bias + exact gelu -> bf16 dst[row*ldc + col]
// EPI 2: bias              -> f32  dst[row*ldc + col]
template <int EPI>
__global__ __launch_bounds__(256, 2)
void gemm_kernel(const ushort_t* __restrict__ A, int lda,
                 const ushort_t* __restrict__ Bt, int ldb,
                 int K,
                 const float* __restrict__ bias,
                 const int* __restrict__ band,
                 void* __restrict__ out, int ldc, int ocol0) {
  __shared__ __align__(16) ushort_t lds[16384];   // A tile [0..8191], B tile [8192..]

  const int tid  = threadIdx.x;
  const int w    = tid >> 6;
  const int lane = tid & 63;
  const int wm = w >> 1, wn = w & 1;
  const int row0 = blockIdx.y << 7;
  const int col0 = blockIdx.x << 7;

  const int L3 = lane >> 3;           // sub-row within 8-row segment
  const int pc = lane & 7;            // lds chunk position this lane fills
  const int gc = (pc ^ L3) * 8;       // swizzled global chunk (elements)
  const int fr = lane & 15;
  const int kg = lane >> 4;

  f32x4 acc[4][4] = {};

  const int KT = K >> 6;
  for (int kt = 0; kt < KT; ++kt) {
    const int k0 = kt << 6;
#pragma unroll
    for (int s = 0; s < 4; ++s) {
      const int seg  = w * 4 + s;
      const int lrow = seg * 8 + L3;
      const ushort_t* ga = A + (size_t)(row0 + lrow) * lda + k0 + gc;
      GLOAD_LDS16(ga, lds + seg * 512);
    }
#pragma unroll
    for (int s = 0; s < 4; ++s) {
      const int seg  = w * 4 + s;
      const int lrow = seg * 8 + L3;
      const ushort_t* gb = Bt + (size_t)(col0 + lrow) * ldb + k0 + gc;
      GLOAD_LDS16(gb, lds + 8192 + seg * 512);
    }
    __syncthreads();   // drains vmcnt -> tiles ready
#pragma unroll
    for (int kk = 0; kk < 2; ++kk) {
      bf16x8 af[4], bfv[4];
#pragma unroll
      for (int mf = 0; mf < 4; ++mf) {
        const int r = wm * 64 + mf * 16 + fr;
        const int c = kk * 4 + kg;
        af[mf] = *(const bf16x8*)(lds + r * 64 + ((c ^ (r & 7)) * 8));
      }
#pragma unroll
      for (int nf = 0; nf < 4; ++nf) {
        const int r = wn * 64 + nf * 16 + fr;
        const int c = kk * 4 + kg;
        bfv[nf] = *(const bf16x8*)(lds + 8192 + r * 64 + ((c ^ (r & 7)) * 8));
      }
#pragma unroll
      for (int mf = 0; mf < 4; ++mf)
#pragma unroll
        for (int nf = 0; nf < 4; ++nf)
          acc[mf][nf] = __builtin_amdgcn_mfma_f32_16x16x32_bf16(
              af[mf], bfv[nf], acc[mf][nf], 0, 0, 0);
    }
    __syncthreads();
  }

  // epilogue: C/D layout col = lane&15 (fr), row = (lane>>4)*4 + reg (kg*4+r)
  const int orow0 = row0 + wm * 64;
  const int ocol0w = col0 + wn * 64;
  if constexpr (EPI == 0) {
    ushort_t* dst = (ushort_t*)out;
#pragma unroll
    for (int mf = 0; mf < 4; ++mf) {
#pragma unroll
      for (int r = 0; r < 4; ++r) {
        const int row = orow0 + mf * 16 + kg * 4 + r;
        const int b = band[row];
#pragma unroll
        for (int nf = 0; nf < 4; ++nf) {
          const int col = ocol0w + nf * 16 + fr;   // 0..127 here
          const float v = acc[mf][nf][r] * 2.0f;   // SCALING = 32/R = 2
          dst[(size_t)row * ldc + ocol0 + col] =
              (b == (col >> 4)) ? f2bf(v) : (ushort_t)0;
        }
      }
    }
  } else if constexpr (EPI == 1) {
    ushort_t* dst = (ushort_t*)out;
#pragma unroll
    for (int mf = 0; mf < 4; ++mf) {
#pragma unroll
      for (int nf = 0; nf < 4; ++nf) {
        const int col = ocol0w + nf * 16 + fr;
        const float bb = bias[col];
#pragma unroll
        for (int r = 0; r < 4; ++r) {
          const int row = orow0 + mf * 16 + kg * 4 + r;
          float v = acc[mf][nf][r] + bb;
          v = 0.5f * v * (1.0f + erff(v * 0.70710678118654752f));  // exact gelu
          dst[(size_t)row * ldc + col] = f2bf(v);
        }
      }
    }
  } else {
    float* dst = (float*)out;
#pragma unroll
    for (int mf = 0; mf < 4; ++mf) {
#pragma unroll
      for (int nf = 0; nf < 4; ++nf) {
        const int col = ocol0w + nf * 16 + fr;
        const float bb = bias[col];
#pragma unroll
        for (int r = 0; r < 4; ++r) {
          const int row = orow0 + mf * 16 + kg * 4 + r;
          dst[(size_t)row * ldc + col] = acc[mf][nf][r] + bb;
        }
      }
    }
  }
}

// ---------------- launch ----------------
extern "C" void kernel_launch(void* const* d_in, const int* in_sizes, int n_in,
                              void* d_out, int out_size, void* d_ws, size_t ws_size,
                              hipStream_t stream) {
  const float* xb = (const float*)d_in[0];   // 65536 x 1025
  const float* W1 = (const float*)d_in[1];   // 1024 x 2048
  const float* b1 = (const float*)d_in[2];   // 2048
  const float* W2 = (const float*)d_in[3];   // 2048 x 1024
  const float* b2 = (const float*)d_in[4];   // 1024
  const float* A1 = (const float*)d_in[5];   // 8 x 1024 x 16
  const float* B1 = (const float*)d_in[6];   // 8 x 16 x 2048
  const float* A2 = (const float*)d_in[7];   // 8 x 2048 x 16
  const float* B2 = (const float*)d_in[8];   // 8 x 16 x 1024

  // workspace carve (all 16B-aligned sizes)
  size_t need = 0;
  char* ws = (char*)d_ws;
  ushort_t* xext = (ushort_t*)(ws + need); need += (size_t)NROWS * KE1 * 2;  // 151 MB
  ushort_t* hext = (ushort_t*)(ws + need); need += (size_t)NROWS * KE2 * 2;  // 285 MB
  int*      band = (int*)(ws + need);      need += (size_t)NROWS * 4;
  ushort_t* w1t  = (ushort_t*)(ws + need); need += (size_t)HID * KE1 * 2;
  ushort_t* w2t  = (ushort_t*)(ws + need); need += (size_t)DIM * KE2 * 2;
  ushort_t* a1t  = (ushort_t*)(ws + need); need += (size_t)128 * DIM * 2;
  ushort_t* a2t  = (ushort_t*)(ws + need); need += (size_t)128 * HID * 2;
  if (ws_size < need) return;  // workspace too small — fail loudly via wrong output

  // prep
  repack_kernel<<<4096, 256, 0, stream>>>(xb, xext, band);
  transpose_f2bf<<<dim3(DIM / 32, HID / 32), dim3(32, 8), 0, stream>>>(W1, w1t, DIM, HID, KE1);
  wt_tail<<<HID, 128, 0, stream>>>(B1, w1t, HID, KE1, DIM);
  transpose_f2bf<<<dim3(HID / 32, DIM / 32), dim3(32, 8), 0, stream>>>(W2, w2t, HID, DIM, KE2);
  wt_tail<<<DIM, 128, 0, stream>>>(B2, w2t, DIM, KE2, HID);
  at_build<<<dim3(DIM / 256, 128), 256, 0, stream>>>(A1, a1t, DIM);
  at_build<<<dim3(HID / 256, 128), 256, 0, stream>>>(A2, a2t, HID);

  // tA1 = x @ A1_all  (K=1024, 128 cols) -> masked/scaled into xext cols 1024..1151
  gemm_kernel<0><<<dim3(1, NROWS / 128), 256, 0, stream>>>(
      xext, KE1, a1t, DIM, DIM, nullptr, band, xext, KE1, DIM);

  // h = gelu(x_ext @ W1t_ext + b1)  (K=1152) -> hext cols 0..2047
  gemm_kernel<1><<<dim3(HID / 128, NROWS / 128), 256, 0, stream>>>(
      xext, KE1, w1t, KE1, KE1, b1, nullptr, hext, KE2, 0);

  // tA2 = h @ A2_all  (K=2048) -> masked/scaled into hext cols 2048..2175
  gemm_kernel<0><<<dim3(1, NROWS / 128), 256, 0, stream>>>(
      hext, KE2, a2t, HID, HID, nullptr, band, hext, KE2, HID);

  // out = h_ext @ W2t_ext + b2  (K=2176) -> f32 d_out
  gemm_kernel<2><<<dim3(DIM / 128, NROWS / 128), 256, 0, stream>>>(
      hext, KE2, w2t, KE2, KE2, b2, nullptr, d_out, DIM, 0);
}